// Round 6
// baseline (299.461 us; speedup 1.0000x reference)
//
#include <hip/hip_runtime.h>

// Problem constants (match the reference)
#define Bv 32
#define Sv 1024
#define Hv 1024
#define Vv 250002

#define GRID   8192                 // 4 waves/block, 1 row/wave -> 32768 rows
#define BLOCK  256
#define NSCAT  64                   // last-64 arrivals perform the scatter
#define ROWS_PER_SCAT ((Bv * Sv) / NSCAT)   // 512

typedef float f4_t __attribute__((ext_vector_type(4)));

// Monotone arrival counter (module-scope, zero-init at load). Each launch adds
// exactly GRID; 2^32 % GRID == 0, so rank = old % GRID is wrap-safe and the
// counter is a multiple of GRID at every call boundary. Work is identical
// every call (which block scatters varies, output does not).
__device__ unsigned g_ctr = 0;

// Fused: zero out[B,V] (device-visible streaming stores, overlapped with the
// row reads) + per-row relu(dot+bias) into tw + last-64-arrival scatter-max.
// atomicMax on the int bit pattern is exact for non-negative floats vs a
// zeroed table (and vs 0xAA poison, which is a negative int). Skipping ids<4
// == reference's final set(0.0) on columns {0..3}.
__global__ __launch_bounds__(BLOCK) void fused_kernel(
        const float* __restrict__ hidden,   // [B*S, H]
        const int*   __restrict__ ids,      // [B*S]
        const float* __restrict__ W,        // [H]
        const float* __restrict__ bias,     // [1]
        float*       __restrict__ out,      // [B, V]
        float*       __restrict__ tw)       // [B*S] workspace
{
    const int bid  = blockIdx.x;
    const int tid  = threadIdx.x;
    const int lane = tid & 63;
    const int wave = tid >> 6;

    // --- Phase Z: one streaming, device-visible zero-store per thread.
    // sc0 sc1 -> visible at device scope on completion (no dirty L2 line that
    // could later evict over a scattered value); nt -> minimal cache pollution
    // so hidden stays L3-resident across graph replays.
    {
        const int i  = bid * BLOCK + tid;
        const int n4 = (Bv * Vv) / 4;          // 2,000,016 (< 8192*256)
        if (i < n4) {
            f4_t z = {0.f, 0.f, 0.f, 0.f};
            f4_t* p = reinterpret_cast<f4_t*>(out) + i;
            asm volatile("global_store_dwordx4 %0, %1, off sc0 sc1 nt"
                         :: "v"(p), "v"(z) : "memory");
        }
    }

    // --- Phase D: one (b,s) row per wave ---
    const int row = bid * 4 + wave;            // [0, 32768)
    const float4* hp = reinterpret_cast<const float4*>(hidden + (size_t)row * Hv);
    const float4* wp = reinterpret_cast<const float4*>(W);

    const float4 h0 = hp[lane];
    const float4 h1 = hp[lane + 64];
    const float4 h2 = hp[lane + 128];
    const float4 h3 = hp[lane + 192];
    const float4 w0 = wp[lane];
    const float4 w1 = wp[lane + 64];
    const float4 w2 = wp[lane + 128];
    const float4 w3 = wp[lane + 192];

    float acc = h0.x * w0.x + h0.y * w0.y + h0.z * w0.z + h0.w * w0.w;
    acc      += h1.x * w1.x + h1.y * w1.y + h1.z * w1.z + h1.w * w1.w;
    acc      += h2.x * w2.x + h2.y * w2.y + h2.z * w2.z + h2.w * w2.w;
    acc      += h3.x * w3.x + h3.y * w3.y + h3.z * w3.z + h3.w * w3.w;

#pragma unroll
    for (int off = 32; off >= 1; off >>= 1)
        acc += __shfl_xor(acc, off, 64);

    if (lane == 0) {
        const float t = fmaxf(acc + bias[0], 0.f);
        // device-visible store so the release fence has no dirty data to flush
        __hip_atomic_store(&tw[row], t, __ATOMIC_RELAXED,
                           __HIP_MEMORY_SCOPE_AGENT);
    }

    // --- Arrival: release + monotone counter ---
    __shared__ unsigned s_old;
    __syncthreads();                 // all threads' stores issued+drained
    if (tid == 0) {
        __threadfence();             // release (cheap: stores already sc1)
        s_old = __hip_atomic_fetch_add(&g_ctr, 1u, __ATOMIC_RELAXED,
                                       __HIP_MEMORY_SCOPE_AGENT);
    }
    __syncthreads();
    const unsigned rank = s_old % GRID;        // block-uniform
    if (rank < GRID - NSCAT) return;           // all but last 64 exit

    // --- Last-64 arrivals: brief spin until every block has arrived ---
    const unsigned target = s_old - rank + GRID;   // count when launch complete
    if (tid == 0) {
        while ((int)(__hip_atomic_load(&g_ctr, __ATOMIC_RELAXED,
                                       __HIP_MEMORY_SCOPE_AGENT) - target) < 0)
            __builtin_amdgcn_s_sleep(16);      // ~430 ns between polls
    }
    __syncthreads();
    __threadfence();                 // acquire

    // --- Phase S: scatter this part's 512 rows (2 per thread) ---
    const int part  = (int)rank - (GRID - NSCAT);  // 0..63
    const int start = part * ROWS_PER_SCAT;
#pragma unroll
    for (int k = 0; k < ROWS_PER_SCAT / BLOCK; ++k) {
        const int i = start + k * BLOCK + tid;
        const float t = __hip_atomic_load(&tw[i], __ATOMIC_RELAXED,
                                          __HIP_MEMORY_SCOPE_AGENT);
        if (t > 0.f) {
            const int id = ids[i];
            if (id >= 4) {
                atomicMax(reinterpret_cast<int*>(out) + (size_t)(i >> 10) * Vv + id,
                          __float_as_int(t));
            }
        }
    }
}

extern "C" void kernel_launch(void* const* d_in, const int* in_sizes, int n_in,
                              void* d_out, int out_size, void* d_ws, size_t ws_size,
                              hipStream_t stream) {
    const float* hidden = (const float*)d_in[0];   // [B, S, H] fp32
    const int*   ids    = (const int*)  d_in[1];   // [B, S] int32
    const float* W      = (const float*)d_in[2];   // [1, H] fp32
    const float* bias   = (const float*)d_in[3];   // [1] fp32
    float*       out    = (float*)d_out;           // [B, V] fp32
    float*       tw     = (float*)d_ws;            // [B*S] = 128 KB scratch

    fused_kernel<<<GRID, BLOCK, 0, stream>>>(hidden, ids, W, bias, out, tw);
}

// Round 7
// 33.337 us; speedup vs baseline: 8.9829x; 8.9829x over previous
//
#include <hip/hip_runtime.h>

// Problem constants (match the reference)
#define Bv 32
#define Sv 1024
#define Hv 1024
#define Vv 250002

#define GRID  8192     // 4 waves/block, 1 row/wave -> 32768 rows
#define BLOCK 256

// ---------------------------------------------------------------------------
// Single fused kernel, NO barrier, NO second launch. Key insight: the output
// is a max-lattice. Every write is an int-bitpattern atomicMax:
//   - zeroing:  atomicMax(cell, 0)        (poison 0xAAAAAAAA is a negative
//                                          int -> becomes 0; never clobbers a
//                                          concurrent scatter value t > 0)
//   - scatter:  atomicMax(cell, bits(t)), t > 0 (also poison-safe)
// max is commutative + idempotent -> zero-pass and scatter need no ordering,
// no device-wide barrier, no cross-XCD store-visibility games (atomics are
// coherent at device scope by construction). Deterministic across graph
// replays: for any initial out state the harness presents (memset-0, 0xAA
// poison, or our own previous identical output), the result is identical.
// Skipping ids<4 == reference's final set(0.0) on columns {0,1,2,3}.
// ---------------------------------------------------------------------------
__global__ __launch_bounds__(BLOCK) void fused_kernel(
        const float* __restrict__ hidden,   // [B*S, H]
        const int*   __restrict__ ids,      // [B*S]
        const float* __restrict__ W,        // [H]
        const float* __restrict__ bias,     // [1]
        float*       __restrict__ out)      // [B, V]
{
    const int bid  = blockIdx.x;
    const int tid  = threadIdx.x;
    const int lane = tid & 63;
    const int wave = tid >> 6;

    // --- issue the row loads first so the HBM read stream starts early ---
    const int row = bid * 4 + wave;            // [0, 32768)
    const float4* hp = reinterpret_cast<const float4*>(hidden + (size_t)row * Hv);
    const float4* wp = reinterpret_cast<const float4*>(W);

    const float4 h0 = hp[lane];
    const float4 h1 = hp[lane + 64];
    const float4 h2 = hp[lane + 128];
    const float4 h3 = hp[lane + 192];
    const float4 w0 = wp[lane];
    const float4 w1 = wp[lane + 64];
    const float4 w2 = wp[lane + 128];
    const float4 w3 = wp[lane + 192];

    // --- zero-pass: 4 coalesced non-returning atomicMax(cell, 0) per thread
    // (fire-and-forget; overlaps the loads above; commutative with scatter) ---
    {
        int* oi = reinterpret_cast<int*>(out);
        const int n = Bv * Vv;                 // 8,000,064 dwords
#pragma unroll
        for (int k = 0; k < 4; ++k) {
            const int g = bid * (BLOCK * 4) + k * BLOCK + tid;
            if (g < n) atomicMax(&oi[g], 0);   // non-returning global_atomic_smax
        }
    }

    // --- dot + butterfly reduce ---
    float acc = h0.x * w0.x + h0.y * w0.y + h0.z * w0.z + h0.w * w0.w;
    acc      += h1.x * w1.x + h1.y * w1.y + h1.z * w1.z + h1.w * w1.w;
    acc      += h2.x * w2.x + h2.y * w2.y + h2.z * w2.z + h2.w * w2.w;
    acc      += h3.x * w3.x + h3.y * w3.y + h3.z * w3.z + h3.w * w3.w;

#pragma unroll
    for (int off = 32; off >= 1; off >>= 1)
        acc += __shfl_xor(acc, off, 64);

    // --- scatter immediately (poison-safe, order-free) ---
    if (lane == 0) {
        const float t = acc + bias[0];
        if (t > 0.f) {
            const int id = ids[row];
            if (id >= 4) {
                const int b = row >> 10;       // S = 1024
                atomicMax(reinterpret_cast<int*>(out) + (size_t)b * Vv + id,
                          __float_as_int(t));
            }
        }
    }
}

extern "C" void kernel_launch(void* const* d_in, const int* in_sizes, int n_in,
                              void* d_out, int out_size, void* d_ws, size_t ws_size,
                              hipStream_t stream) {
    const float* hidden = (const float*)d_in[0];   // [B, S, H] fp32
    const int*   ids    = (const int*)  d_in[1];   // [B, S] int32
    const float* W      = (const float*)d_in[2];   // [1, H] fp32
    const float* bias   = (const float*)d_in[3];   // [1] fp32
    float*       out    = (float*)d_out;           // [B, V] fp32

    fused_kernel<<<GRID, BLOCK, 0, stream>>>(hidden, ids, W, bias, out);
}

// Round 8
// 31.245 us; speedup vs baseline: 9.5844x; 1.0670x over previous
//
#include <hip/hip_runtime.h>

// Problem constants (match the reference)
#define Bv 32
#define Sv 1024
#define Hv 1024
#define Vv 250002

#define GRID  4096     // 4 waves/block, 2 rows/wave -> 8 rows/block -> 32768 rows
#define BLOCK 256

typedef float f4_t __attribute__((ext_vector_type(4)));

// ---------------------------------------------------------------------------
// K1 (proven R5 skeleton + MLP tuning):
//   - each wave computes TWO (b,s) rows (8 outstanding dwordx4 loads/wave)
//   - all global loads are issued BEFORE the fire-and-forget zero-stores,
//     so the latency-critical read stream leads the store stream
//   - zero-stores are nontemporal (don't evict L3-resident hidden between
//     graph replays; R2 measured ~50% L3 hit on hidden)
//   - two independent butterfly reductions interleave for ILP
// Scatter is deferred to K2: the inter-dispatch release/acquire makes the
// zero-stores safely visible to K2's cross-XCD atomics (barrier-free
// in-kernel alternatives measured worse: R2 285us, R6 299us, R7 33.3us).
// ---------------------------------------------------------------------------
__global__ __launch_bounds__(BLOCK) void k1_zero_dot(
        const float* __restrict__ hidden,   // [B*S, H]
        const float* __restrict__ W,        // [H]
        const float* __restrict__ bias,     // [1]
        float*       __restrict__ out,      // [B, V]
        float*       __restrict__ tw)       // [B*S] workspace
{
    const int bid  = blockIdx.x;
    const int tid  = threadIdx.x;
    const int lane = tid & 63;
    const int wave = tid >> 6;

    const int row0 = bid * 8 + wave * 2;       // [0, 32768), two rows per wave
    const float4* hp0 = reinterpret_cast<const float4*>(hidden + (size_t)row0 * Hv);
    const float4* hp1 = reinterpret_cast<const float4*>(hidden + (size_t)(row0 + 1) * Hv);
    const float4* wp  = reinterpret_cast<const float4*>(W);

    // --- issue all reads first (8 row loads + 4 W loads in flight) ---
    const float4 a0 = hp0[lane];
    const float4 a1 = hp0[lane + 64];
    const float4 a2 = hp0[lane + 128];
    const float4 a3 = hp0[lane + 192];
    const float4 b0 = hp1[lane];
    const float4 b1 = hp1[lane + 64];
    const float4 b2 = hp1[lane + 128];
    const float4 b3 = hp1[lane + 192];
    const float4 w0 = wp[lane];
    const float4 w1 = wp[lane + 64];
    const float4 w2 = wp[lane + 128];
    const float4 w3 = wp[lane + 192];

    // --- fire-and-forget zero of out (2 nt stores/thread; 2,097,152 slots
    //     cover the 2,000,016 float4 of out) ---
    {
        f4_t* out4 = reinterpret_cast<f4_t*>(out);
        const int n4 = (Bv * Vv) / 4;
        const f4_t z = {0.f, 0.f, 0.f, 0.f};
#pragma unroll
        for (int k = 0; k < 2; ++k) {
            const int i = (bid * 2 + k) * BLOCK + tid;
            if (i < n4) __builtin_nontemporal_store(z, &out4[i]);
        }
    }

    // --- two dots + interleaved butterfly reductions ---
    float acc0 = a0.x * w0.x + a0.y * w0.y + a0.z * w0.z + a0.w * w0.w;
    float acc1 = b0.x * w0.x + b0.y * w0.y + b0.z * w0.z + b0.w * w0.w;
    acc0      += a1.x * w1.x + a1.y * w1.y + a1.z * w1.z + a1.w * w1.w;
    acc1      += b1.x * w1.x + b1.y * w1.y + b1.z * w1.z + b1.w * w1.w;
    acc0      += a2.x * w2.x + a2.y * w2.y + a2.z * w2.z + a2.w * w2.w;
    acc1      += b2.x * w2.x + b2.y * w2.y + b2.z * w2.z + b2.w * w2.w;
    acc0      += a3.x * w3.x + a3.y * w3.y + a3.z * w3.z + a3.w * w3.w;
    acc1      += b3.x * w3.x + b3.y * w3.y + b3.z * w3.z + b3.w * w3.w;

#pragma unroll
    for (int off = 32; off >= 1; off >>= 1) {
        acc0 += __shfl_xor(acc0, off, 64);
        acc1 += __shfl_xor(acc1, off, 64);
    }

    if (lane == 0) {
        const float b = bias[0];
        tw[row0]     = fmaxf(acc0 + b, 0.f);
        tw[row0 + 1] = fmaxf(acc1 + b, 0.f);
    }
}

// ---------------------------------------------------------------------------
// K2: scatter-max. atomicMax on the int bit pattern is exact for non-negative
// floats vs a zero-initialized table; skipping ids<4 == reference's final
// set(0.0) on columns {0,1,2,3}.
// ---------------------------------------------------------------------------
__global__ __launch_bounds__(256) void k2_scatter(
        const float* __restrict__ tw,       // [B*S]
        const int*   __restrict__ ids,      // [B*S]
        float*       __restrict__ out)      // [B, V]
{
    const int i = blockIdx.x * 256 + threadIdx.x;   // [0, 32768)
    const float t = tw[i];
    if (t > 0.f) {
        const int id = ids[i];
        if (id >= 4) {
            const int b = i >> 10;   // S = 1024
            atomicMax(reinterpret_cast<int*>(out + (size_t)b * Vv + id),
                      __float_as_int(t));
        }
    }
}

extern "C" void kernel_launch(void* const* d_in, const int* in_sizes, int n_in,
                              void* d_out, int out_size, void* d_ws, size_t ws_size,
                              hipStream_t stream) {
    const float* hidden = (const float*)d_in[0];   // [B, S, H] fp32
    const int*   ids    = (const int*)  d_in[1];   // [B, S] int32
    const float* W      = (const float*)d_in[2];   // [1, H] fp32
    const float* bias   = (const float*)d_in[3];   // [1] fp32
    float*       out    = (float*)d_out;           // [B, V] fp32
    float*       tw     = (float*)d_ws;            // [B*S] = 128 KB scratch

    k1_zero_dot<<<GRID, BLOCK, 0, stream>>>(hidden, W, bias, out, tw);
    k2_scatter<<<(Bv * Sv) / 256, 256, 0, stream>>>(tw, ids, out);
}

// Round 9
// 30.724 us; speedup vs baseline: 9.7468x; 1.0169x over previous
//
#include <hip/hip_runtime.h>

// Problem constants (match the reference)
#define Bv 32
#define Sv 1024
#define Hv 1024
#define Vv 250002

#define GRID  8192     // 4 waves/block, 1 row/wave -> 32768 rows (R5 proven)
#define BLOCK 256

typedef float f4_t __attribute__((ext_vector_type(4)));

// ---------------------------------------------------------------------------
// K1 — exact R5 structure (best measured: 29.85 us total):
//   - one nontemporal zero-store of out per thread (overlaps the read stream;
//     nt keeps L3 space for hidden, which is ~50% L3-served on replays)
//   - one 4 KB hidden row per wave: 4 x float4/lane coalesced, dot with
//     register-held W, 64-lane butterfly, lane 0 writes relu(dot+bias) -> tw
// Scatter deferred to K2 (inter-dispatch ordering makes zero-stores visible
// to cross-XCD atomics; all in-kernel alternatives measured worse:
// R2 285us spin-flood, R6 299us sc0/sc1 writes at 76 GB/s, R7 +3.5us atomics).
// ---------------------------------------------------------------------------
__global__ __launch_bounds__(BLOCK) void k1_zero_dot(
        const float* __restrict__ hidden,   // [B*S, H]
        const float* __restrict__ W,        // [H]
        const float* __restrict__ bias,     // [1]
        float*       __restrict__ out,      // [B, V]
        float*       __restrict__ tw)       // [B*S] workspace
{
    const int bid  = blockIdx.x;
    const int tid  = threadIdx.x;
    const int lane = tid & 63;
    const int wave = tid >> 6;

    // --- zero slice: one nt float4 store per thread (fire-and-forget) ---
    {
        f4_t* out4 = reinterpret_cast<f4_t*>(out);
        const int n4 = (Bv * Vv) / 4;          // 2,000,016 (< 8192*256)
        const int i  = bid * BLOCK + tid;
        if (i < n4) {
            f4_t z = {0.f, 0.f, 0.f, 0.f};
            __builtin_nontemporal_store(z, &out4[i]);
        }
    }

    // --- one (b,s) row per wave ---
    const int row = bid * 4 + wave;            // [0, 32768)
    const float4* hp = reinterpret_cast<const float4*>(hidden + (size_t)row * Hv);
    const float4* wp = reinterpret_cast<const float4*>(W);

    const float4 h0 = hp[lane];
    const float4 h1 = hp[lane + 64];
    const float4 h2 = hp[lane + 128];
    const float4 h3 = hp[lane + 192];
    const float4 w0 = wp[lane];
    const float4 w1 = wp[lane + 64];
    const float4 w2 = wp[lane + 128];
    const float4 w3 = wp[lane + 192];

    float acc = h0.x * w0.x + h0.y * w0.y + h0.z * w0.z + h0.w * w0.w;
    acc      += h1.x * w1.x + h1.y * w1.y + h1.z * w1.z + h1.w * w1.w;
    acc      += h2.x * w2.x + h2.y * w2.y + h2.z * w2.z + h2.w * w2.w;
    acc      += h3.x * w3.x + h3.y * w3.y + h3.z * w3.z + h3.w * w3.w;

#pragma unroll
    for (int off = 32; off >= 1; off >>= 1)
        acc += __shfl_xor(acc, off, 64);

    if (lane == 0)
        tw[row] = fmaxf(acc + bias[0], 0.f);
}

// ---------------------------------------------------------------------------
// K2 — vectorized scatter: 4 rows/thread via float4(tw) + int4(ids);
// 8192 threads in 32 blocks. S=1024 is divisible by 4, so a 4-row group
// never straddles a batch boundary: batch = group >> 8.
// atomicMax on the int bit pattern is exact for non-negative floats vs a
// zeroed table; skipping ids<4 == reference's final set(0.0) on cols {0..3}.
// ---------------------------------------------------------------------------
__global__ __launch_bounds__(256) void k2_scatter(
        const float4* __restrict__ tw4,     // [B*S/4]
        const int4*   __restrict__ ids4,    // [B*S/4]
        float*        __restrict__ out)     // [B, V]
{
    const int g = blockIdx.x * 256 + threadIdx.x;   // [0, 8192) row-groups
    const float4 t  = tw4[g];
    const int4   id = ids4[g];
    int* ob = reinterpret_cast<int*>(out) + (size_t)(g >> 8) * Vv;  // batch row

    if (t.x > 0.f && id.x >= 4) atomicMax(&ob[id.x], __float_as_int(t.x));
    if (t.y > 0.f && id.y >= 4) atomicMax(&ob[id.y], __float_as_int(t.y));
    if (t.z > 0.f && id.z >= 4) atomicMax(&ob[id.z], __float_as_int(t.z));
    if (t.w > 0.f && id.w >= 4) atomicMax(&ob[id.w], __float_as_int(t.w));
}

extern "C" void kernel_launch(void* const* d_in, const int* in_sizes, int n_in,
                              void* d_out, int out_size, void* d_ws, size_t ws_size,
                              hipStream_t stream) {
    const float* hidden = (const float*)d_in[0];   // [B, S, H] fp32
    const int*   ids    = (const int*)  d_in[1];   // [B, S] int32
    const float* W      = (const float*)d_in[2];   // [1, H] fp32
    const float* bias   = (const float*)d_in[3];   // [1] fp32
    float*       out    = (float*)d_out;           // [B, V] fp32
    float*       tw     = (float*)d_ws;            // [B*S] = 128 KB scratch

    k1_zero_dot<<<GRID, BLOCK, 0, stream>>>(hidden, W, bias, out, tw);
    k2_scatter<<<(Bv * Sv) / 4 / 256, 256, 0, stream>>>(
        reinterpret_cast<const float4*>(tw),
        reinterpret_cast<const int4*>(ids), out);
}

// Round 10
// 29.815 us; speedup vs baseline: 10.0438x; 1.0305x over previous
//
#include <hip/hip_runtime.h>

// Problem constants (match the reference)
#define Bv 32
#define Sv 1024
#define Hv 1024
#define Vv 250002

#define K1_GRID 8192     // 4 waves/block, 1 row per wave -> 32768 rows
#define BLOCK   256

typedef float f4_t __attribute__((ext_vector_type(4)));   // native vec for nontemporal

// ---------------------------------------------------------------------------
// R5 structure — measured best (29.85 us) across 8 variants:
//   R2  in-kernel spin barrier          285 us  (same-address poll flood)
//   R3  two-role grid (phases serialize) 32.5 us
//   R6  sc0/sc1 coherent zero-stores    299 us  (write-through = 76 GB/s)
//   R7  atomicMax-as-zero fused         33.3 us (8M atomics > K2 launch)
//   R8  2 rows/wave                     31.2 us (TLP loss > MLP gain)
//   R9  vectorized K2 (4 rows/thread)   30.7 us (atomic chains serialize)
// K1: overlapped nt zero-stores + one 4KB row per wave, register-held W,
//     64-lane butterfly; lane 0 writes relu(dot+bias) -> tw.
// K2: scalar scatter-max (atomicMax on int bit pattern — exact for
//     non-negative floats vs zeroed table; skipping ids<4 == reference's
//     final set(0.0) on columns {0..3}).
// The K1/K2 split is load-bearing: the inter-dispatch boundary is the only
// cheap device-wide release/acquire for the 33 MB of zero-stores on gfx950.
// ---------------------------------------------------------------------------
__global__ __launch_bounds__(BLOCK) void k1_zero_dot(
        const float* __restrict__ hidden,   // [B*S, H]
        const float* __restrict__ W,        // [H]
        const float* __restrict__ bias,     // [1]
        float*       __restrict__ out,      // [B, V]
        float*       __restrict__ tw)       // [B*S] (workspace)
{
    const int bid  = blockIdx.x;
    const int tid  = threadIdx.x;
    const int lane = tid & 63;
    const int wave = tid >> 6;

    // --- role 1: zero slice (fire-and-forget; overlaps everything below) ---
    {
        f4_t* out4 = reinterpret_cast<f4_t*>(out);
        const int n4 = (Bv * Vv) / 4;          // 2,000,016
        const int i  = bid * BLOCK + tid;
        if (i < n4) {
            f4_t z = {0.f, 0.f, 0.f, 0.f};
            __builtin_nontemporal_store(z, &out4[i]);
        }
    }

    // --- role 2: one (b,s) row per wave ---
    const int row = bid * 4 + wave;            // [0, 32768)

    const float4* hp = reinterpret_cast<const float4*>(hidden + (size_t)row * Hv);
    const float4* wp = reinterpret_cast<const float4*>(W);

    const float4 h0 = hp[lane];
    const float4 h1 = hp[lane + 64];
    const float4 h2 = hp[lane + 128];
    const float4 h3 = hp[lane + 192];
    const float4 w0 = wp[lane];
    const float4 w1 = wp[lane + 64];
    const float4 w2 = wp[lane + 128];
    const float4 w3 = wp[lane + 192];

    float acc = h0.x * w0.x + h0.y * w0.y + h0.z * w0.z + h0.w * w0.w;
    acc      += h1.x * w1.x + h1.y * w1.y + h1.z * w1.z + h1.w * w1.w;
    acc      += h2.x * w2.x + h2.y * w2.y + h2.z * w2.z + h2.w * w2.w;
    acc      += h3.x * w3.x + h3.y * w3.y + h3.z * w3.z + h3.w * w3.w;

#pragma unroll
    for (int off = 32; off >= 1; off >>= 1)
        acc += __shfl_xor(acc, off, 64);

    if (lane == 0)
        tw[row] = fmaxf(acc + bias[0], 0.f);
}

__global__ __launch_bounds__(256) void k2_scatter(
        const float* __restrict__ tw,       // [B*S]
        const int*   __restrict__ ids,      // [B*S]
        float*       __restrict__ out)      // [B, V]
{
    const int i = blockIdx.x * 256 + threadIdx.x;   // [0, 32768)
    const float t = tw[i];
    if (t > 0.f) {
        const int id = ids[i];
        if (id >= 4) {
            const int b = i >> 10;   // S = 1024
            atomicMax(reinterpret_cast<int*>(out + (size_t)b * Vv + id),
                      __float_as_int(t));
        }
    }
}

extern "C" void kernel_launch(void* const* d_in, const int* in_sizes, int n_in,
                              void* d_out, int out_size, void* d_ws, size_t ws_size,
                              hipStream_t stream) {
    const float* hidden = (const float*)d_in[0];   // [B, S, H] fp32
    const int*   ids    = (const int*)  d_in[1];   // [B, S] int32
    const float* W      = (const float*)d_in[2];   // [1, H] fp32
    const float* bias   = (const float*)d_in[3];   // [1] fp32
    float*       out    = (float*)d_out;           // [B, V] fp32
    float*       tw     = (float*)d_ws;            // [B*S] = 128 KB scratch

    k1_zero_dot<<<K1_GRID, BLOCK, 0, stream>>>(hidden, W, bias, out, tw);
    k2_scatter<<<(Bv * Sv) / 256, 256, 0, stream>>>(tw, ids, out);
}